// Round 4
// baseline (465.429 us; speedup 1.0000x reference)
//
#include <hip/hip_runtime.h>
#include <hip/hip_bf16.h>
#include <stdint.h>

// Problem dims
#define DMODEL 1024
#define DHID   1024
#define NBATCH 8
#define LSEQ   2048
#define MROWS  (NBATCH * LSEQ)   // 16384
#define KCAT   2048              // [h | x] concat K
#define CH     32                // scan chunk length
#define NCH    64                // LSEQ / CH
#define BH     (NBATCH * DHID)   // 8192
#define CPT    4                 // channels per scan thread

typedef __attribute__((ext_vector_type(8))) short  short8;
typedef __attribute__((ext_vector_type(4))) short  s16x4;
typedef __attribute__((ext_vector_type(8))) __bf16 bf16x8;
typedef __attribute__((ext_vector_type(4))) float  f32x4;

__device__ __forceinline__ unsigned short f2bf(float f) {
  union { float f; unsigned int u; } v; v.f = f;
  unsigned int u = v.u;
  u += 0x7fffu + ((u >> 16) & 1u);   // round-to-nearest-even
  return (unsigned short)(u >> 16);
}

__device__ __forceinline__ float bf2f(unsigned short s) {
  union { unsigned int u; float f; } v; v.u = ((unsigned int)s) << 16;
  return v.f;
}

__device__ __forceinline__ float softplus_f(float x) {
  return fmaxf(x, 0.f) + log1pf(expf(-fabsf(x)));   // == jax.nn.softplus
}

__device__ __forceinline__ short8 pack8(float4 a, float4 b) {
  short8 o;
  o[0] = (short)f2bf(a.x); o[1] = (short)f2bf(a.y);
  o[2] = (short)f2bf(a.z); o[3] = (short)f2bf(a.w);
  o[4] = (short)f2bf(b.x); o[5] = (short)f2bf(b.y);
  o[6] = (short)f2bf(b.z); o[7] = (short)f2bf(b.w);
  return o;
}

// ---- one cast kernel: x -> A2[:,1024:], W1=[dw;Bw], W2=[Cw|Dw] -----------
__global__ __launch_bounds__(256)
void cast_all_kernel(const float* __restrict__ x,
                     const float* __restrict__ dw, const float* __restrict__ Bw,
                     const float* __restrict__ Cw, const float* __restrict__ Dw,
                     unsigned short* __restrict__ A2,
                     unsigned short* __restrict__ W1, unsigned short* __restrict__ W2) {
  const size_t MX = (size_t)MROWS * 1024;       // 16M: x
  const size_t M1 = (size_t)1024 * 1024;        // 1M
  size_t i8 = ((size_t)blockIdx.x * 256 + threadIdx.x) * 8;
  if (i8 < MX) {
    size_t row = i8 >> 10; int col = (int)(i8 & 1023);
    const float4* p = (const float4*)(x + i8);
    *(short8*)(A2 + row * (size_t)KCAT + 1024 + col) = pack8(p[0], p[1]);
  } else if (i8 < MX + 2 * M1) {                // W1 rows 0..1023=dw, 1024..2047=Bw
    size_t k = i8 - MX;
    const float* src = (k < M1) ? (dw + k) : (Bw + k - M1);
    const float4* p = (const float4*)src;
    *(short8*)(W1 + k) = pack8(p[0], p[1]);
  } else {                                      // W2 row d: [Cw[d,:] | Dw[d,:]]
    size_t k = i8 - MX - 2 * M1;
    size_t d = k >> 11; int c = (int)(k & 2047);
    const float* src = (c < 1024) ? (Cw + d * 1024 + c) : (Dw + d * 1024 + (c - 1024));
    const float4* p = (const float4*)src;
    *(short8*)(W2 + k) = pack8(p[0], p[1]);
  }
}

// ---- GEMM: C[M,N] = A[M,K] @ B[N,K]^T ------------------------------------
// 128x128 tile, 4 waves (2M x 2N), BK=32, 3-buffer LDS ring (48 KiB total)
// -> 3 blocks/CU resident (TLP = the proven lever: round0 occ37% beat the
// 1-block/CU 256^2 variants).  Prefetch 2 tiles ahead; end-of-tile wait is
// counted vmcnt(4) (tile t+1 landed, t+2 in flight) -- no drain in the loop.
// LDS per buffer: A (4096 shorts) then B (4096), fragment-major:
//   element A[row=f*16+l16][col=quad*8+j] at short-offset f*512 + lane*8
// -> every ds_read_b128 is base + lane*16B (conflict-free, measured 0 in r2/r3);
// global_load_lds linear dest matches via pre-permuted global source (m173).

__device__ __forceinline__ void stage128(const unsigned short* __restrict__ gbase,
                                         int ld, int k0,
                                         unsigned short* sbase,
                                         int wave, int quad, int l16) {
#pragma unroll
  for (int s = 0; s < 2; ++s) {
    int f = s * 4 + wave;                                   // wave-uniform frag id
    const unsigned short* g = gbase + (size_t)(f * 16 + l16) * ld + k0 + quad * 8;
    unsigned short* sd = sbase + (size_t)f * 512;           // uniform base (+lane*16B)
    __builtin_amdgcn_global_load_lds(
        (const __attribute__((address_space(1))) unsigned int*)g,
        (__attribute__((address_space(3))) unsigned int*)sd, 16, 0, 0);
  }
}

// mode 0: f32 out, += bias0[n]+bias1[n];  mode 1: bf16 out, no bias
__global__ __launch_bounds__(256, 3)
void gemm_bt(const unsigned short* __restrict__ A, int lda,
             const unsigned short* __restrict__ B, int ldb,
             void* __restrict__ Cp, int ldc, int K, int mode,
             const float* __restrict__ bias0, const float* __restrict__ bias1) {
  __shared__ __align__(16) unsigned short smem[3 * 8192];   // 48 KiB ring
  const int tid  = threadIdx.x;
  const int lane = tid & 63;
  const int wave = tid >> 6;         // 0..3
  const int quad = lane >> 4, l16 = lane & 15;
  const int wm = (wave & 1) * 64, wn = (wave >> 1) * 64;

  // XCD-aware swizzle: each XCD (bid%8) owns a contiguous M-band, N-fastest.
  // Bijective: Mt divisible by 8 (Mt=128 here).
  const int Nt = gridDim.x, Mt = gridDim.y;
  int bid  = blockIdx.y * Nt + blockIdx.x;
  int xcd  = bid & 7;
  int slot = bid >> 3;
  int lm = slot / Nt;
  int ln = slot - lm * Nt;
  const int m0 = (xcd * (Mt >> 3) + lm) * 128;
  const int n0 = ln * 128;

  const unsigned short* Ab = A + (size_t)m0 * lda;
  const unsigned short* Bb = B + (size_t)n0 * ldb;

  const int nt = K >> 5;             // K-tiles of 32 (>= 32 for our shapes)

  f32x4 acc[4][4] = {};

  // ---- prologue: stage tiles 0 (buf0) and 1 (buf1); wait tile 0 ----------
  stage128(Ab, lda, 0, smem, wave, quad, l16);
  stage128(Bb, ldb, 0, smem + 4096, wave, quad, l16);
  stage128(Ab, lda, 32, smem + 8192, wave, quad, l16);
  stage128(Bb, ldb, 32, smem + 8192 + 4096, wave, quad, l16);
  asm volatile("s_waitcnt vmcnt(4)" ::: "memory");   // tile 0 landed; tile 1 in flight
  __builtin_amdgcn_s_barrier();
  __builtin_amdgcn_sched_barrier(0);

  // ---- main loop: 1 barrier/tile, counted vmcnt, ring of 3 ---------------
  int ci = 0;   // t % 3  (buffer being read)
  int si = 2;   // (t+2) % 3 (buffer being staged)
  for (int t = 0; t < nt; ++t) {
    if (t + 2 < nt) {                       // issue prefetch of tile t+2
      unsigned short* nb = smem + si * 8192;
      stage128(Ab, lda, (t + 2) * 32, nb, wave, quad, l16);
      stage128(Bb, ldb, (t + 2) * 32, nb + 4096, wave, quad, l16);
    }
    const unsigned short* As = smem + ci * 8192;
    const unsigned short* Bs = As + 4096;
    short8 af[4], bfr[4];
#pragma unroll
    for (int i = 0; i < 4; ++i)
      af[i] = *(const short8*)(As + (size_t)(((wave & 1) * 4 + i)) * 512 + lane * 8);
#pragma unroll
    for (int j = 0; j < 4; ++j)
      bfr[j] = *(const short8*)(Bs + (size_t)(((wave >> 1) * 4 + j)) * 512 + lane * 8);
#pragma unroll
    for (int i = 0; i < 4; ++i)
#pragma unroll
      for (int j = 0; j < 4; ++j)
        acc[i][j] = __builtin_amdgcn_mfma_f32_16x16x32_bf16(
            __builtin_bit_cast(bf16x8, af[i]),
            __builtin_bit_cast(bf16x8, bfr[j]), acc[i][j], 0, 0, 0);
    // end-of-tile: tile t+1 must have landed; keep t+2 in flight
    if (t + 2 < nt)      { asm volatile("s_waitcnt vmcnt(4)" ::: "memory"); }
    else if (t + 1 < nt) { asm volatile("s_waitcnt vmcnt(0)" ::: "memory"); }
    __builtin_amdgcn_s_barrier();
    __builtin_amdgcn_sched_barrier(0);
    ci = (ci == 2) ? 0 : ci + 1;
    si = (si == 2) ? 0 : si + 1;
  }

  // ---- epilogue: C-write (verified mapping: col=lane&15, row=quad*4+r) ---
  if (mode == 0) {
    float* C = (float*)Cp;
#pragma unroll
    for (int i = 0; i < 4; ++i)
#pragma unroll
      for (int j = 0; j < 4; ++j) {
        int n  = n0 + wn + j * 16 + l16;
        int mb = m0 + wm + i * 16 + quad * 4;
        float badd = bias0[n] + bias1[n];
#pragma unroll
        for (int r = 0; r < 4; ++r)
          C[(size_t)(mb + r) * ldc + n] = acc[i][j][r] + badd;
      }
  } else {
    unsigned short* C16 = (unsigned short*)Cp;
#pragma unroll
    for (int i = 0; i < 4; ++i)
#pragma unroll
      for (int j = 0; j < 4; ++j) {
        int n  = n0 + wn + j * 16 + l16;
        int mb = m0 + wm + i * 16 + quad * 4;
#pragma unroll
        for (int r = 0; r < 4; ++r)
          C16[(size_t)(mb + r) * ldc + n] = f2bf(acc[i][j][r]);
      }
  }
}

// ---- scan pass A: pointwise (in-place) + per-chunk carries --------------
__global__ __launch_bounds__(256)
void scan_carry_kernel(unsigned short* __restrict__ G1,
                       const float* __restrict__ Av, const float* __restrict__ Bbv,
                       const float* __restrict__ dbv, float2* __restrict__ carr) {
  int t = blockIdx.x * 256 + threadIdx.x;      // 131072 = 8 * 64 * 256
  int ho = t & 255, chunk = (t >> 8) & (NCH - 1), b = t >> 14;
  int h0 = ho << 2;
  float4 A0 = *(const float4*)(Av + h0);
  float4 B0 = *(const float4*)(Bbv + h0);
  float4 D0 = *(const float4*)(dbv + h0);
  float Ah[4]  = {A0.x, A0.y, A0.z, A0.w};
  float Bbh[4] = {B0.x, B0.y, B0.z, B0.w};
  float dbh[4] = {D0.x, D0.y, D0.z, D0.w};
  unsigned short* base = G1 + ((size_t)(b * LSEQ + chunk * CH)) * KCAT + h0;
  float hs[4] = {}, sd[4] = {};
  s16x4 dp = *(const s16x4*)(base);
  s16x4 bp = *(const s16x4*)(base + 1024);
#pragma unroll 4
  for (int l = 0; l < CH; ++l) {
    s16x4 dpn = dp, bpn = bp;
    if (l + 1 < CH) {                           // prefetch next step
      dpn = *(const s16x4*)(base + (size_t)(l + 1) * KCAT);
      bpn = *(const s16x4*)(base + (size_t)(l + 1) * KCAT + 1024);
    }
    s16x4 dq, bq;
#pragma unroll
    for (int j = 0; j < 4; ++j) {
      float d = softplus_f(bf2f((unsigned short)dp[j]) + dbh[j]);
      unsigned short dr = f2bf(d);
      float drf = bf2f(dr);
      float bb = drf * (bf2f((unsigned short)bp[j]) + Bbh[j]);
      unsigned short br = f2bf(bb);
      sd[j] += drf;
      float a = __expf(drf * Ah[j]);
      hs[j] = fmaf(a, hs[j], bf2f(br));
      dq[j] = (short)dr; bq[j] = (short)br;
    }
    *(s16x4*)(base + (size_t)l * KCAT) = dq;
    *(s16x4*)(base + (size_t)l * KCAT + 1024) = bq;
    dp = dpn; bp = bpn;
  }
  float2* cb = carr + (size_t)chunk * BH + b * 1024 + h0;
#pragma unroll
  for (int j = 0; j < 4; ++j)
    cb[j] = make_float2(__expf(Ah[j] * sd[j]), hs[j]);
}

// ---- scan pass B: compose carries (lane-contiguous) ---------------------
__global__ __launch_bounds__(256)
void scan_comb_kernel(const float2* __restrict__ carr, float* __restrict__ Hc) {
  int t = blockIdx.x * 256 + threadIdx.x;   // 8192 = B*DH
  float H = 0.f;
#pragma unroll
  for (int c = 0; c < NCH; ++c) {
    float2 ah = carr[(size_t)c * BH + t];
    Hc[(size_t)c * BH + t] = H;              // carry-in for chunk c
    H = fmaf(ah.x, H, ah.y);
  }
}

// ---- scan pass C: recompute with carry, emit h bf16 into A2[:,0:1024] ---
__global__ __launch_bounds__(256)
void scan_final_kernel(const unsigned short* __restrict__ G1,
                       const float* __restrict__ Av, const float* __restrict__ Hc,
                       unsigned short* __restrict__ A2) {
  int t = blockIdx.x * 256 + threadIdx.x;      // 131072
  int ho = t & 255, chunk = (t >> 8) & (NCH - 1), b = t >> 14;
  int h0 = ho << 2;
  float4 A0 = *(const float4*)(Av + h0);
  float Ah[4] = {A0.x, A0.y, A0.z, A0.w};
  const unsigned short* base = G1 + ((size_t)(b * LSEQ + chunk * CH)) * KCAT + h0;
  unsigned short* obase = A2 + ((size_t)(b * LSEQ + chunk * CH)) * KCAT + h0;
  const float* hb = Hc + (size_t)chunk * BH + b * 1024 + h0;
  float hs[4];
#pragma unroll
  for (int j = 0; j < 4; ++j) hs[j] = hb[j];
  s16x4 dp = *(const s16x4*)(base);
  s16x4 bp = *(const s16x4*)(base + 1024);
#pragma unroll 4
  for (int l = 0; l < CH; ++l) {
    s16x4 dpn = dp, bpn = bp;
    if (l + 1 < CH) {                           // prefetch next step
      dpn = *(const s16x4*)(base + (size_t)(l + 1) * KCAT);
      bpn = *(const s16x4*)(base + (size_t)(l + 1) * KCAT + 1024);
    }
    s16x4 o;
#pragma unroll
    for (int j = 0; j < 4; ++j) {
      float d = bf2f((unsigned short)dp[j]);
      float a = __expf(d * Ah[j]);
      hs[j] = fmaf(a, hs[j], bf2f((unsigned short)bp[j]));
      o[j] = (short)f2bf(hs[j]);
    }
    *(s16x4*)(obase + (size_t)l * KCAT) = o;
    dp = dpn; bp = bpn;
  }
}

extern "C" void kernel_launch(void* const* d_in, const int* in_sizes, int n_in,
                              void* d_out, int out_size, void* d_ws, size_t ws_size,
                              hipStream_t stream) {
  const float* x  = (const float*)d_in[0];
  const float* Av = (const float*)d_in[1];
  const float* Bw = (const float*)d_in[2];
  const float* Bb = (const float*)d_in[3];
  const float* Cw = (const float*)d_in[4];
  const float* Cb = (const float*)d_in[5];
  const float* Dw = (const float*)d_in[6];
  const float* Db = (const float*)d_in[7];
  const float* dw = (const float*)d_in[8];
  const float* db = (const float*)d_in[9];
  float* out = (float*)d_out;

  // Workspace (138 MiB, same as proven rounds):
  //   A2 [16384,2048] bf16 = 64 MiB ([h | x])
  //   G1 [16384,2048] bf16 = 64 MiB ([dpre|bpre] -> in-place [d|bb])
  //   W1 [2048,1024]  bf16 =  4 MiB ([dw;Bw]; reused as carr after GEMM1)
  //   W2 [1024,2048]  bf16 =  4 MiB ([Cw|Dw])
  //   Hc [64,8192]    f32  =  2 MiB
  const size_t sz_big = (size_t)MROWS * KCAT * 2;
  const size_t sz_w   = (size_t)2048 * 1024 * 2;
  const size_t sz_hc  = (size_t)NCH * BH * 4;
  const size_t need = 2 * sz_big + 2 * sz_w + sz_hc;
  if (ws_size < need) return;

  char* w = (char*)d_ws;
  unsigned short* A2 = (unsigned short*)w; w += sz_big;
  unsigned short* G1 = (unsigned short*)w; w += sz_big;
  unsigned short* W1 = (unsigned short*)w; w += sz_w;
  unsigned short* W2 = (unsigned short*)w; w += sz_w;
  float* Hc = (float*)w;                   w += sz_hc;
  float2* carr = (float2*)W1;  // W1 dead after GEMM1; carr = NCH*BH*8 = 4 MiB exactly

  // cast everything (x, W1, W2) in one launch
  const size_t cast_elems = (size_t)MROWS * 1024 + 2 * (size_t)2048 * 1024;
  cast_all_kernel<<<(int)(cast_elems / (256 * 8)), 256, 0, stream>>>(
      x, dw, Bw, Cw, Dw, A2, W1, W2);

  // GEMM1: G1 = x @ [dw;Bw]^T -> [dpre | bpre]  (M=16384,N=2048,K=1024), bf16
  dim3 g1(KCAT / 128, MROWS / 128);        // (16, 128) = 2048 blocks
  gemm_bt<<<g1, 256, 0, stream>>>(A2 + 1024, KCAT, W1, 1024, G1, KCAT, 1024, 1,
                                  nullptr, nullptr);

  // chunked scan: pointwise (softplus once, in-place) + carries, compose, final
  scan_carry_kernel<<<(NBATCH * NCH * (DHID / CPT)) / 256, 256, 0, stream>>>(
      G1, Av, Bb, db, carr);
  scan_comb_kernel<<<BH / 256, 256, 0, stream>>>(carr, Hc);
  scan_final_kernel<<<(NBATCH * NCH * (DHID / CPT)) / 256, 256, 0, stream>>>(
      G1, Av, Hc, A2);

  // GEMM2: out = [h | x] @ [Cw|Dw]^T + Cb + Db  (M=16384,N=1024,K=2048), f32
  dim3 g2(DMODEL / 128, MROWS / 128);      // (8, 128) = 1024 blocks
  gemm_bt<<<g2, 256, 0, stream>>>(A2, KCAT, W2, KCAT, out, DMODEL, KCAT, 0, Cb, Db);
}

// Round 5
// 395.512 us; speedup vs baseline: 1.1768x; 1.1768x over previous
//
#include <hip/hip_runtime.h>
#include <hip/hip_bf16.h>
#include <stdint.h>

// Problem dims
#define DMODEL 1024
#define DHID   1024
#define NBATCH 8
#define LSEQ   2048
#define MROWS  (NBATCH * LSEQ)   // 16384
#define KCAT   2048              // [h | x] concat K
#define CH     32                // scan chunk length
#define NCH    64                // LSEQ / CH
#define BH     (NBATCH * DHID)   // 8192
#define CPT    4                 // channels per scan thread

typedef __attribute__((ext_vector_type(8))) short  short8;
typedef __attribute__((ext_vector_type(4))) short  s16x4;
typedef __attribute__((ext_vector_type(8))) __bf16 bf16x8;
typedef __attribute__((ext_vector_type(4))) float  f32x4;

__device__ __forceinline__ unsigned short f2bf(float f) {
  union { float f; unsigned int u; } v; v.f = f;
  unsigned int u = v.u;
  u += 0x7fffu + ((u >> 16) & 1u);   // round-to-nearest-even
  return (unsigned short)(u >> 16);
}

__device__ __forceinline__ float bf2f(unsigned short s) {
  union { unsigned int u; float f; } v; v.u = ((unsigned int)s) << 16;
  return v.f;
}

__device__ __forceinline__ float softplus_f(float x) {
  return fmaxf(x, 0.f) + log1pf(expf(-fabsf(x)));   // == jax.nn.softplus
}

__device__ __forceinline__ short8 pack8(float4 a, float4 b) {
  short8 o;
  o[0] = (short)f2bf(a.x); o[1] = (short)f2bf(a.y);
  o[2] = (short)f2bf(a.z); o[3] = (short)f2bf(a.w);
  o[4] = (short)f2bf(b.x); o[5] = (short)f2bf(b.y);
  o[6] = (short)f2bf(b.z); o[7] = (short)f2bf(b.w);
  return o;
}

// ---- one cast kernel: x -> A2[:,1024:], W1 (interleaved dw/Bw), W2 -------
// W1 row 2h = dw[h,:], row 2h+1 = Bw[h,:]  -> G1 columns become (d,bb) pairs
__global__ __launch_bounds__(256)
void cast_all_kernel(const float* __restrict__ x,
                     const float* __restrict__ dw, const float* __restrict__ Bw,
                     const float* __restrict__ Cw, const float* __restrict__ Dw,
                     unsigned short* __restrict__ A2,
                     unsigned short* __restrict__ W1, unsigned short* __restrict__ W2) {
  const size_t MX = (size_t)MROWS * 1024;       // 16M: x
  const size_t M1 = (size_t)1024 * 1024;        // 1M
  size_t i8 = ((size_t)blockIdx.x * 256 + threadIdx.x) * 8;
  if (i8 < MX) {
    size_t row = i8 >> 10; int col = (int)(i8 & 1023);
    const float4* p = (const float4*)(x + i8);
    *(short8*)(A2 + row * (size_t)KCAT + 1024 + col) = pack8(p[0], p[1]);
  } else if (i8 < MX + 2 * M1) {                // W1 interleaved: row r, h=r>>1
    size_t k = i8 - MX;
    size_t h = k >> 11;                          // channel
    int c = (int)(k & 1023);                     // column
    const float* src = ((k >> 10) & 1) ? (Bw + h * 1024 + c) : (dw + h * 1024 + c);
    const float4* p = (const float4*)src;
    *(short8*)(W1 + k) = pack8(p[0], p[1]);
  } else {                                      // W2 row d: [Cw[d,:] | Dw[d,:]]
    size_t k = i8 - MX - 2 * M1;
    size_t d = k >> 11; int c = (int)(k & 2047);
    const float* src = (c < 1024) ? (Cw + d * 1024 + c) : (Dw + d * 1024 + (c - 1024));
    const float4* p = (const float4*)src;
    *(short8*)(W2 + k) = pack8(p[0], p[1]);
  }
}

// ---- GEMM: C[M,N] = A[M,K] @ B[N,K]^T ------------------------------------
// EXACT round-0 structure (proven 89.4 us x5): 128^2 tile, 4 waves, single
// 16 KiB LDS double-array, 2 syncthreads/K-step. Schedule rewrites (counted
// vmcnt rings, 256^2 8-phase variants) all measured slower at these shapes.
// mode 0: f32 out, += bias0[n]+bias1[n]
// mode 2: SSM pointwise epilogue (GEMM1): n even -> d=softplus(acc+db[h]),
//         n odd -> bb = d_neighbor * (acc + Bb[h]); bf16 out. h = n>>1.
__device__ __forceinline__ void stage_tile(const unsigned short* g0, int ld,
                                           unsigned short* s0, int t, int lane) {
#pragma unroll
  for (int half = 0; half < 2; ++half) {
    int c = t + half * 256;
    const unsigned short* g = g0 + (size_t)(c >> 2) * ld + (c & 3) * 8;
    unsigned short* s = s0 + ((size_t)(t - lane) + half * 256) * 8; // wave-uniform base
    __builtin_amdgcn_global_load_lds(
        (const __attribute__((address_space(1))) unsigned int*)g,
        (__attribute__((address_space(3))) unsigned int*)s, 16, 0, 0);
  }
}

__global__ __launch_bounds__(256, 4)
void gemm_bt(const unsigned short* __restrict__ A, int lda,
             const unsigned short* __restrict__ B, int ldb,
             void* __restrict__ Cp, int ldc, int K, int mode,
             const float* __restrict__ bias0, const float* __restrict__ bias1) {
  __shared__ __align__(16) unsigned short As[128 * 32];
  __shared__ __align__(16) unsigned short Bs[128 * 32];
  const int t = threadIdx.x;
  const int lane = t & 63, wave = t >> 6;
  const int quad = lane >> 4, l16 = lane & 15;

  // XCD-aware swizzle: each XCD (bid%8) owns a contiguous M-band, N-fastest,
  // so the weight matrix stays resident in that XCD's 4 MB L2.
  const int Nt = gridDim.x, Mt = gridDim.y;
  int bid = blockIdx.y * Nt + blockIdx.x;
  int xcd = bid & 7;
  int slot = bid >> 3;
  int lm = slot / Nt;
  int ln = slot - lm * Nt;
  const int m0 = (xcd * (Mt >> 3) + lm) * 128;
  const int n0 = ln * 128;

  const int wm = (wave & 1) * 64, wn = (wave >> 1) * 64;

  const unsigned short* Ab = A + (size_t)m0 * lda;
  const unsigned short* Bb = B + (size_t)n0 * ldb;

  f32x4 acc[4][4] = {};

  for (int k0 = 0; k0 < K; k0 += 32) {
    stage_tile(Ab + k0, lda, As, t, lane);
    stage_tile(Bb + k0, ldb, Bs, t, lane);
    __syncthreads();
    short8 af[4], bfr[4];
#pragma unroll
    for (int i = 0; i < 4; ++i)
      af[i] = *(const short8*)(As + ((size_t)(wm + i * 16 + l16)) * 32 + quad * 8);
#pragma unroll
    for (int j = 0; j < 4; ++j)
      bfr[j] = *(const short8*)(Bs + ((size_t)(wn + j * 16 + l16)) * 32 + quad * 8);
#pragma unroll
    for (int i = 0; i < 4; ++i)
#pragma unroll
      for (int j = 0; j < 4; ++j)
        acc[i][j] = __builtin_amdgcn_mfma_f32_16x16x32_bf16(
            __builtin_bit_cast(bf16x8, af[i]),
            __builtin_bit_cast(bf16x8, bfr[j]), acc[i][j], 0, 0, 0);
    __syncthreads();
  }

  if (mode == 0) {
    float* C = (float*)Cp;
#pragma unroll
    for (int i = 0; i < 4; ++i)
#pragma unroll
      for (int j = 0; j < 4; ++j) {
        int n = n0 + wn + j * 16 + l16;
        int mb = m0 + wm + i * 16 + quad * 4;
        float badd = bias0[n] + bias1[n];
#pragma unroll
        for (int r = 0; r < 4; ++r)
          C[(size_t)(mb + r) * ldc + n] = acc[i][j][r] + badd;
      }
  } else {
    // mode 2: fused SSM pointwise. Adjacent lanes hold (dpre, bpre) of the
    // same channel h (W1 rows interleaved); one shfl_xor(1) moves d across.
    unsigned short* C16 = (unsigned short*)Cp;
#pragma unroll
    for (int i = 0; i < 4; ++i)
#pragma unroll
      for (int j = 0; j < 4; ++j) {
        int n = n0 + wn + j * 16 + l16;
        int mb = m0 + wm + i * 16 + quad * 4;
        int h = n >> 1;
        bool isd = (n & 1) == 0;
        float bias = isd ? bias0[h] : bias1[h];   // db[h] : Bb[h]
#pragma unroll
        for (int r = 0; r < 4; ++r) {
          float v = acc[i][j][r] + bias;          // dpre+db  or  bpre+Bb
          float d = softplus_f(v);                // valid on even lanes
          float dn = __shfl_xor(d, 1);            // neighbor's d (for odd lanes)
          float ov = isd ? d : dn * v;            // d  or  bb = d*(bpre+Bb)
          C16[(size_t)(mb + r) * ldc + n] = f2bf(ov);
        }
      }
  }
}

// ---- scan pass A: per-chunk carries (G1 is read-only now) ---------------
// G1 row layout: [d0,bb0,d1,bb1,...] interleaved pairs (2048 wide).
// Thread handles 4 channels -> one contiguous 16B short8 per row.
__global__ __launch_bounds__(256)
void scan_carry_kernel(const unsigned short* __restrict__ G1,
                       const float* __restrict__ Av, float2* __restrict__ carr) {
  int t = blockIdx.x * 256 + threadIdx.x;      // 131072 = 8 * 64 * 256
  int ho = t & 255, chunk = (t >> 8) & (NCH - 1), b = t >> 14;
  int h0 = ho << 2;
  float4 A0 = *(const float4*)(Av + h0);
  float Ah[4] = {A0.x, A0.y, A0.z, A0.w};
  const unsigned short* base = G1 + ((size_t)(b * LSEQ + chunk * CH)) * KCAT + 2 * h0;
  float hs[4] = {}, sd[4] = {};
  short8 v = *(const short8*)(base);
#pragma unroll 4
  for (int l = 0; l < CH; ++l) {
    short8 vn = v;
    if (l + 1 < CH)                              // prefetch next step
      vn = *(const short8*)(base + (size_t)(l + 1) * KCAT);
#pragma unroll
    for (int j = 0; j < 4; ++j) {
      float d  = bf2f((unsigned short)v[2 * j]);
      float bb = bf2f((unsigned short)v[2 * j + 1]);
      sd[j] += d;
      hs[j] = fmaf(__expf(d * Ah[j]), hs[j], bb);
    }
    v = vn;
  }
  float2* cb = carr + (size_t)chunk * BH + b * 1024 + h0;
#pragma unroll
  for (int j = 0; j < 4; ++j)
    cb[j] = make_float2(__expf(Ah[j] * sd[j]), hs[j]);
}

// ---- scan pass B: compose carries (lane-contiguous) ---------------------
__global__ __launch_bounds__(256)
void scan_comb_kernel(const float2* __restrict__ carr, float* __restrict__ Hc) {
  int t = blockIdx.x * 256 + threadIdx.x;   // 8192 = B*DH
  float H = 0.f;
#pragma unroll
  for (int c = 0; c < NCH; ++c) {
    float2 ah = carr[(size_t)c * BH + t];
    Hc[(size_t)c * BH + t] = H;              // carry-in for chunk c
    H = fmaf(ah.x, H, ah.y);
  }
}

// ---- scan pass C: recompute with carry, emit h bf16 into A2[:,0:1024] ---
__global__ __launch_bounds__(256)
void scan_final_kernel(const unsigned short* __restrict__ G1,
                       const float* __restrict__ Av, const float* __restrict__ Hc,
                       unsigned short* __restrict__ A2) {
  int t = blockIdx.x * 256 + threadIdx.x;      // 131072
  int ho = t & 255, chunk = (t >> 8) & (NCH - 1), b = t >> 14;
  int h0 = ho << 2;
  float4 A0 = *(const float4*)(Av + h0);
  float Ah[4] = {A0.x, A0.y, A0.z, A0.w};
  const unsigned short* base = G1 + ((size_t)(b * LSEQ + chunk * CH)) * KCAT + 2 * h0;
  unsigned short* obase = A2 + ((size_t)(b * LSEQ + chunk * CH)) * KCAT + h0;
  const float* hb = Hc + (size_t)chunk * BH + b * 1024 + h0;
  float hs[4];
#pragma unroll
  for (int j = 0; j < 4; ++j) hs[j] = hb[j];
  short8 v = *(const short8*)(base);
#pragma unroll 4
  for (int l = 0; l < CH; ++l) {
    short8 vn = v;
    if (l + 1 < CH)                              // prefetch next step
      vn = *(const short8*)(base + (size_t)(l + 1) * KCAT);
    s16x4 o;
#pragma unroll
    for (int j = 0; j < 4; ++j) {
      float d  = bf2f((unsigned short)v[2 * j]);
      float bb = bf2f((unsigned short)v[2 * j + 1]);
      hs[j] = fmaf(__expf(d * Ah[j]), hs[j], bb);
      o[j] = (short)f2bf(hs[j]);
    }
    *(s16x4*)(obase + (size_t)l * KCAT) = o;
    v = vn;
  }
}

extern "C" void kernel_launch(void* const* d_in, const int* in_sizes, int n_in,
                              void* d_out, int out_size, void* d_ws, size_t ws_size,
                              hipStream_t stream) {
  const float* x  = (const float*)d_in[0];
  const float* Av = (const float*)d_in[1];
  const float* Bw = (const float*)d_in[2];
  const float* Bb = (const float*)d_in[3];
  const float* Cw = (const float*)d_in[4];
  const float* Cb = (const float*)d_in[5];
  const float* Dw = (const float*)d_in[6];
  const float* Db = (const float*)d_in[7];
  const float* dw = (const float*)d_in[8];
  const float* db = (const float*)d_in[9];
  float* out = (float*)d_out;

  // Workspace (138 MiB):
  //   A2 [16384,2048] bf16 = 64 MiB ([h | x])
  //   G1 [16384,2048] bf16 = 64 MiB ((d,bb) interleaved pairs)
  //   W1 [2048,1024]  bf16 =  4 MiB (interleaved dw/Bw; reused as carr)
  //   W2 [1024,2048]  bf16 =  4 MiB ([Cw|Dw])
  //   Hc [64,8192]    f32  =  2 MiB
  const size_t sz_big = (size_t)MROWS * KCAT * 2;
  const size_t sz_w   = (size_t)2048 * 1024 * 2;
  const size_t sz_hc  = (size_t)NCH * BH * 4;
  const size_t need = 2 * sz_big + 2 * sz_w + sz_hc;
  if (ws_size < need) return;

  char* w = (char*)d_ws;
  unsigned short* A2 = (unsigned short*)w; w += sz_big;
  unsigned short* G1 = (unsigned short*)w; w += sz_big;
  unsigned short* W1 = (unsigned short*)w; w += sz_w;
  unsigned short* W2 = (unsigned short*)w; w += sz_w;
  float* Hc = (float*)w;                   w += sz_hc;
  float2* carr = (float2*)W1;  // W1 dead after GEMM1; carr = NCH*BH*8 = 4 MiB exactly

  // cast everything (x, W1, W2) in one launch
  const size_t cast_elems = (size_t)MROWS * 1024 + 2 * (size_t)2048 * 1024;
  cast_all_kernel<<<(int)(cast_elems / (256 * 8)), 256, 0, stream>>>(
      x, dw, Bw, Cw, Dw, A2, W1, W2);

  // GEMM1 + fused pointwise: G1 = pointwise(x @ W1^T)  (M=16384,N=2048,K=1024)
  dim3 g1(KCAT / 128, MROWS / 128);        // (16, 128)
  gemm_bt<<<g1, 256, 0, stream>>>(A2 + 1024, KCAT, W1, 1024, G1, KCAT, 1024, 2,
                                  db, Bb);

  // chunked scan: carries (read-only over G1), compose, final
  scan_carry_kernel<<<(NBATCH * NCH * (DHID / CPT)) / 256, 256, 0, stream>>>(
      G1, Av, carr);
  scan_comb_kernel<<<BH / 256, 256, 0, stream>>>(carr, Hc);
  scan_final_kernel<<<(NBATCH * NCH * (DHID / CPT)) / 256, 256, 0, stream>>>(
      G1, Av, Hc, A2);

  // GEMM2: out = [h | x] @ [Cw|Dw]^T + Cb + Db  (M=16384,N=1024,K=2048), f32
  dim3 g2(DMODEL / 128, MROWS / 128);      // (8, 128)
  gemm_bt<<<g2, 256, 0, stream>>>(A2, KCAT, W2, KCAT, out, DMODEL, KCAT, 0, Cb, Db);
}

// Round 7
// 339.407 us; speedup vs baseline: 1.3713x; 1.1653x over previous
//
#include <hip/hip_runtime.h>
#include <hip/hip_bf16.h>
#include <stdint.h>

// Problem dims
#define DMODEL 1024
#define DHID   1024
#define NBATCH 8
#define LSEQ   2048
#define MROWS  (NBATCH * LSEQ)   // 16384
#define KCAT   2048              // [h | x] concat K
#define CH     32                // scan chunk length
#define NCH    64                // LSEQ / CH
#define BH     (NBATCH * DHID)   // 8192
#define CPT    4                 // channels per scan thread

typedef __attribute__((ext_vector_type(8))) short  short8;
typedef __attribute__((ext_vector_type(4))) short  s16x4;
typedef __attribute__((ext_vector_type(8))) __bf16 bf16x8;
typedef __attribute__((ext_vector_type(4))) float  f32x4;

__device__ __forceinline__ unsigned short f2bf(float f) {
  union { float f; unsigned int u; } v; v.f = f;
  unsigned int u = v.u;
  u += 0x7fffu + ((u >> 16) & 1u);   // round-to-nearest-even
  return (unsigned short)(u >> 16);
}

__device__ __forceinline__ float bf2f(unsigned short s) {
  union { unsigned int u; float f; } v; v.u = ((unsigned int)s) << 16;
  return v.f;
}

// Fast softplus: hardware v_exp_f32/v_log_f32 (~10 VALU ops) instead of libm
// expf+log1pf (~50-70 branchy ops -- measured as +79us VALU in the round-5
// fused epilogue, VALUBusy 81%). Max abs error ~6e-8 (at tiny d), far below
// the bf16 rounding already applied to d (rel ~0.4%).
__device__ __forceinline__ float softplus_f(float x) {
  return fmaxf(x, 0.f) + __logf(1.f + __expf(-fabsf(x)));
}

__device__ __forceinline__ short8 pack8(float4 a, float4 b) {
  short8 o;
  o[0] = (short)f2bf(a.x); o[1] = (short)f2bf(a.y);
  o[2] = (short)f2bf(a.z); o[3] = (short)f2bf(a.w);
  o[4] = (short)f2bf(b.x); o[5] = (short)f2bf(b.y);
  o[6] = (short)f2bf(b.z); o[7] = (short)f2bf(b.w);
  return o;
}

// ---- one cast kernel: x -> A2[:,1024:], W1 (interleaved dw/Bw), W2 -------
// W1 row 2h = dw[h,:], row 2h+1 = Bw[h,:]  -> G1 columns become (d,bb) pairs
__global__ __launch_bounds__(256)
void cast_all_kernel(const float* __restrict__ x,
                     const float* __restrict__ dw, const float* __restrict__ Bw,
                     const float* __restrict__ Cw, const float* __restrict__ Dw,
                     unsigned short* __restrict__ A2,
                     unsigned short* __restrict__ W1, unsigned short* __restrict__ W2) {
  const size_t MX = (size_t)MROWS * 1024;       // 16M: x
  const size_t M1 = (size_t)1024 * 1024;        // 1M
  size_t i8 = ((size_t)blockIdx.x * 256 + threadIdx.x) * 8;
  if (i8 < MX) {
    size_t row = i8 >> 10; int col = (int)(i8 & 1023);
    const float4* p = (const float4*)(x + i8);
    *(short8*)(A2 + row * (size_t)KCAT + 1024 + col) = pack8(p[0], p[1]);
  } else if (i8 < MX + 2 * M1) {                // W1 interleaved: row r, h=r>>1
    size_t k = i8 - MX;
    size_t h = k >> 11;                          // channel
    int c = (int)(k & 1023);                     // column
    const float* src = ((k >> 10) & 1) ? (Bw + h * 1024 + c) : (dw + h * 1024 + c);
    const float4* p = (const float4*)src;
    *(short8*)(W1 + k) = pack8(p[0], p[1]);
  } else {                                      // W2 row d: [Cw[d,:] | Dw[d,:]]
    size_t k = i8 - MX - 2 * M1;
    size_t d = k >> 11; int c = (int)(k & 2047);
    const float* src = (c < 1024) ? (Cw + d * 1024 + c) : (Dw + d * 1024 + (c - 1024));
    const float4* p = (const float4*)src;
    *(short8*)(W2 + k) = pack8(p[0], p[1]);
  }
}

// ---- GEMM: C[M,N] = A[M,K] @ B[N,K]^T ------------------------------------
// EXACT round-0 structure (proven 89.4 us x5): 128^2 tile, 4 waves, single
// 16 KiB LDS double-array, 2 syncthreads/K-step. Schedule rewrites (counted
// vmcnt rings, 256^2 8-phase variants) all measured slower at these shapes.
// mode 0: f32 out, += bias0[n]+bias1[n]
// mode 2: SSM pointwise epilogue (GEMM1): n even -> d=softplus(acc+db[h]),
//         n odd -> bb = d_neighbor * (acc + Bb[h]); bf16 out. h = n>>1.
__device__ __forceinline__ void stage_tile(const unsigned short* g0, int ld,
                                           unsigned short* s0, int t, int lane) {
#pragma unroll
  for (int half = 0; half < 2; ++half) {
    int c = t + half * 256;
    const unsigned short* g = g0 + (size_t)(c >> 2) * ld + (c & 3) * 8;
    unsigned short* s = s0 + ((size_t)(t - lane) + half * 256) * 8; // wave-uniform base
    __builtin_amdgcn_global_load_lds(
        (const __attribute__((address_space(1))) unsigned int*)g,
        (__attribute__((address_space(3))) unsigned int*)s, 16, 0, 0);
  }
}

__global__ __launch_bounds__(256, 4)
void gemm_bt(const unsigned short* __restrict__ A, int lda,
             const unsigned short* __restrict__ B, int ldb,
             void* __restrict__ Cp, int ldc, int K, int mode,
             const float* __restrict__ bias0, const float* __restrict__ bias1) {
  __shared__ __align__(16) unsigned short As[128 * 32];
  __shared__ __align__(16) unsigned short Bs[128 * 32];
  const int t = threadIdx.x;
  const int lane = t & 63, wave = t >> 6;
  const int quad = lane >> 4, l16 = lane & 15;

  // XCD-aware swizzle: each XCD (bid%8) owns a contiguous M-band, N-fastest,
  // so the weight matrix stays resident in that XCD's 4 MB L2.
  const int Nt = gridDim.x, Mt = gridDim.y;
  int bid = blockIdx.y * Nt + blockIdx.x;
  int xcd = bid & 7;
  int slot = bid >> 3;
  int lm = slot / Nt;
  int ln = slot - lm * Nt;
  const int m0 = (xcd * (Mt >> 3) + lm) * 128;
  const int n0 = ln * 128;

  const int wm = (wave & 1) * 64, wn = (wave >> 1) * 64;

  const unsigned short* Ab = A + (size_t)m0 * lda;
  const unsigned short* Bb = B + (size_t)n0 * ldb;

  f32x4 acc[4][4] = {};

  for (int k0 = 0; k0 < K; k0 += 32) {
    stage_tile(Ab + k0, lda, As, t, lane);
    stage_tile(Bb + k0, ldb, Bs, t, lane);
    __syncthreads();
    short8 af[4], bfr[4];
#pragma unroll
    for (int i = 0; i < 4; ++i)
      af[i] = *(const short8*)(As + ((size_t)(wm + i * 16 + l16)) * 32 + quad * 8);
#pragma unroll
    for (int j = 0; j < 4; ++j)
      bfr[j] = *(const short8*)(Bs + ((size_t)(wn + j * 16 + l16)) * 32 + quad * 8);
#pragma unroll
    for (int i = 0; i < 4; ++i)
#pragma unroll
      for (int j = 0; j < 4; ++j)
        acc[i][j] = __builtin_amdgcn_mfma_f32_16x16x32_bf16(
            __builtin_bit_cast(bf16x8, af[i]),
            __builtin_bit_cast(bf16x8, bfr[j]), acc[i][j], 0, 0, 0);
    __syncthreads();
  }

  if (mode == 0) {
    float* C = (float*)Cp;
#pragma unroll
    for (int i = 0; i < 4; ++i)
#pragma unroll
      for (int j = 0; j < 4; ++j) {
        int n = n0 + wn + j * 16 + l16;
        int mb = m0 + wm + i * 16 + quad * 4;
        float badd = bias0[n] + bias1[n];
#pragma unroll
        for (int r = 0; r < 4; ++r)
          C[(size_t)(mb + r) * ldc + n] = acc[i][j][r] + badd;
      }
  } else {
    // mode 2: fused SSM pointwise. Adjacent lanes hold (dpre, bpre) of the
    // same channel h (W1 rows interleaved); one shfl_xor(1) moves d across.
    unsigned short* C16 = (unsigned short*)Cp;
#pragma unroll
    for (int i = 0; i < 4; ++i)
#pragma unroll
      for (int j = 0; j < 4; ++j) {
        int n = n0 + wn + j * 16 + l16;
        int mb = m0 + wm + i * 16 + quad * 4;
        int h = n >> 1;
        bool isd = (n & 1) == 0;
        float bias = isd ? bias0[h] : bias1[h];   // db[h] : Bb[h]
#pragma unroll
        for (int r = 0; r < 4; ++r) {
          float v = acc[i][j][r] + bias;          // dpre+db  or  bpre+Bb
          float d = softplus_f(v);                // valid on even lanes
          float dn = __shfl_xor(d, 1);            // neighbor's d (for odd lanes)
          float ov = isd ? d : dn * v;            // d  or  bb = d*(bpre+Bb)
          C16[(size_t)(mb + r) * ldc + n] = f2bf(ov);
        }
      }
  }
}

// ---- scan pass A: per-chunk carries (G1 is read-only now) ---------------
// G1 row layout: [d0,bb0,d1,bb1,...] interleaved pairs (2048 wide).
// Thread handles 4 channels -> one contiguous 16B short8 per row.
__global__ __launch_bounds__(256)
void scan_carry_kernel(const unsigned short* __restrict__ G1,
                       const float* __restrict__ Av, float2* __restrict__ carr) {
  int t = blockIdx.x * 256 + threadIdx.x;      // 131072 = 8 * 64 * 256
  int ho = t & 255, chunk = (t >> 8) & (NCH - 1), b = t >> 14;
  int h0 = ho << 2;
  float4 A0 = *(const float4*)(Av + h0);
  float Ah[4] = {A0.x, A0.y, A0.z, A0.w};
  const unsigned short* base = G1 + ((size_t)(b * LSEQ + chunk * CH)) * KCAT + 2 * h0;
  float hs[4] = {}, sd[4] = {};
  short8 v = *(const short8*)(base);
#pragma unroll 4
  for (int l = 0; l < CH; ++l) {
    short8 vn = v;
    if (l + 1 < CH)                              // prefetch next step
      vn = *(const short8*)(base + (size_t)(l + 1) * KCAT);
#pragma unroll
    for (int j = 0; j < 4; ++j) {
      float d  = bf2f((unsigned short)v[2 * j]);
      float bb = bf2f((unsigned short)v[2 * j + 1]);
      sd[j] += d;
      hs[j] = fmaf(__expf(d * Ah[j]), hs[j], bb);
    }
    v = vn;
  }
  float2* cb = carr + (size_t)chunk * BH + b * 1024 + h0;
#pragma unroll
  for (int j = 0; j < 4; ++j)
    cb[j] = make_float2(__expf(Ah[j] * sd[j]), hs[j]);
}

// ---- scan pass B: compose carries (lane-contiguous) ---------------------
__global__ __launch_bounds__(256)
void scan_comb_kernel(const float2* __restrict__ carr, float* __restrict__ Hc) {
  int t = blockIdx.x * 256 + threadIdx.x;   // 8192 = B*DH
  float H = 0.f;
#pragma unroll
  for (int c = 0; c < NCH; ++c) {
    float2 ah = carr[(size_t)c * BH + t];
    Hc[(size_t)c * BH + t] = H;              // carry-in for chunk c
    H = fmaf(ah.x, H, ah.y);
  }
}

// ---- scan pass C: recompute with carry, emit h bf16 into A2[:,0:1024] ---
__global__ __launch_bounds__(256)
void scan_final_kernel(const unsigned short* __restrict__ G1,
                       const float* __restrict__ Av, const float* __restrict__ Hc,
                       unsigned short* __restrict__ A2) {
  int t = blockIdx.x * 256 + threadIdx.x;      // 131072
  int ho = t & 255, chunk = (t >> 8) & (NCH - 1), b = t >> 14;
  int h0 = ho << 2;
  float4 A0 = *(const float4*)(Av + h0);
  float Ah[4] = {A0.x, A0.y, A0.z, A0.w};
  const unsigned short* base = G1 + ((size_t)(b * LSEQ + chunk * CH)) * KCAT + 2 * h0;
  unsigned short* obase = A2 + ((size_t)(b * LSEQ + chunk * CH)) * KCAT + h0;
  const float* hb = Hc + (size_t)chunk * BH + b * 1024 + h0;
  float hs[4];
#pragma unroll
  for (int j = 0; j < 4; ++j) hs[j] = hb[j];
  short8 v = *(const short8*)(base);
#pragma unroll 4
  for (int l = 0; l < CH; ++l) {
    short8 vn = v;
    if (l + 1 < CH)                              // prefetch next step
      vn = *(const short8*)(base + (size_t)(l + 1) * KCAT);
    s16x4 o;
#pragma unroll
    for (int j = 0; j < 4; ++j) {
      float d  = bf2f((unsigned short)v[2 * j]);
      float bb = bf2f((unsigned short)v[2 * j + 1]);
      hs[j] = fmaf(__expf(d * Ah[j]), hs[j], bb);
      o[j] = (short)f2bf(hs[j]);
    }
    *(s16x4*)(obase + (size_t)l * KCAT) = o;
    v = vn;
  }
}

extern "C" void kernel_launch(void* const* d_in, const int* in_sizes, int n_in,
                              void* d_out, int out_size, void* d_ws, size_t ws_size,
                              hipStream_t stream) {
  const float* x  = (const float*)d_in[0];
  const float* Av = (const float*)d_in[1];
  const float* Bw = (const float*)d_in[2];
  const float* Bb = (const float*)d_in[3];
  const float* Cw = (const float*)d_in[4];
  const float* Cb = (const float*)d_in[5];
  const float* Dw = (const float*)d_in[6];
  const float* Db = (const float*)d_in[7];
  const float* dw = (const float*)d_in[8];
  const float* db = (const float*)d_in[9];
  float* out = (float*)d_out;

  // Workspace (138 MiB):
  //   A2 [16384,2048] bf16 = 64 MiB ([h | x])
  //   G1 [16384,2048] bf16 = 64 MiB ((d,bb) interleaved pairs)
  //   W1 [2048,1024]  bf16 =  4 MiB (interleaved dw/Bw; reused as carr)
  //   W2 [1024,2048]  bf16 =  4 MiB ([Cw|Dw])
  //   Hc [64,8192]    f32  =  2 MiB
  const size_t sz_big = (size_t)MROWS * KCAT * 2;
  const size_t sz_w   = (size_t)2048 * 1024 * 2;
  const size_t sz_hc  = (size_t)NCH * BH * 4;
  const size_t need = 2 * sz_big + 2 * sz_w + sz_hc;
  if (ws_size < need) return;

  char* w = (char*)d_ws;
  unsigned short* A2 = (unsigned short*)w; w += sz_big;
  unsigned short* G1 = (unsigned short*)w; w += sz_big;
  unsigned short* W1 = (unsigned short*)w; w += sz_w;
  unsigned short* W2 = (unsigned short*)w; w += sz_w;
  float* Hc = (float*)w;                   w += sz_hc;
  float2* carr = (float2*)W1;  // W1 dead after GEMM1; carr = NCH*BH*8 = 4 MiB exactly

  // cast everything (x, W1, W2) in one launch
  const size_t cast_elems = (size_t)MROWS * 1024 + 2 * (size_t)2048 * 1024;
  cast_all_kernel<<<(int)(cast_elems / (256 * 8)), 256, 0, stream>>>(
      x, dw, Bw, Cw, Dw, A2, W1, W2);

  // GEMM1 + fused pointwise: G1 = pointwise(x @ W1^T)  (M=16384,N=2048,K=1024)
  dim3 g1(KCAT / 128, MROWS / 128);        // (16, 128)
  gemm_bt<<<g1, 256, 0, stream>>>(A2 + 1024, KCAT, W1, 1024, G1, KCAT, 1024, 2,
                                  db, Bb);

  // chunked scan: carries (read-only over G1), compose, final
  scan_carry_kernel<<<(NBATCH * NCH * (DHID / CPT)) / 256, 256, 0, stream>>>(
      G1, Av, carr);
  scan_comb_kernel<<<BH / 256, 256, 0, stream>>>(carr, Hc);
  scan_final_kernel<<<(NBATCH * NCH * (DHID / CPT)) / 256, 256, 0, stream>>>(
      G1, Av, Hc, A2);

  // GEMM2: out = [h | x] @ [Cw|Dw]^T + Cb + Db  (M=16384,N=1024,K=2048), f32
  dim3 g2(DMODEL / 128, MROWS / 128);      // (8, 128)
  gemm_bt<<<g2, 256, 0, stream>>>(A2, KCAT, W2, KCAT, out, DMODEL, KCAT, 0, Cb, Db);
}